// Round 7
// baseline (183.403 us; speedup 1.0000x reference)
//
#include <hip/hip_runtime.h>

#define LAMC    10000.0f
#define INV_LAM 1e-4f
#define EPSC    1e-12f
#define TOLC    1e-6f
#define BLK     256
#define WPB     (BLK / 64)   // waves per block
#define RPW     256          // rows per wave (2 pairs/thread * 2 rows * 64 lanes)

__device__ __forceinline__ float frcp(float x)  { return __builtin_amdgcn_rcpf(x); }
__device__ __forceinline__ float frsq(float x)  { return __builtin_amdgcn_rsqf(x); }
__device__ __forceinline__ float fsqrt_(float x){ return __builtin_amdgcn_sqrtf(x); }

// sign(phi(t)) without sqrt/div: phi = L - R*sqrt(q), q >= EPS > 0
__device__ __forceinline__ bool phi_pos(float t, float A, float p, float N, float b) {
    float q  = fmaxf(fmaf(t, fmaf(t, A, -2.0f * p), N), EPSC);
    float L  = fmaf(-t, A, p);        // p - t*A   (U_MAX = 1)
    float R  = fmaf(t, INV_LAM, b);   // b + t/LAM
    float L2 = L * L;
    float Rq = (R * R) * q;
    return (R < 0.0f) ? ((L >= 0.0f) || (L2 < Rq))
                      : ((L >  0.0f) && (L2 > Rq));
}

// branch-3 solve with proven tight bracket (phi has a unique sign change):
//  - p>0, R(p/A)>=0 : root in (0, p/A];  - p>0, R(p/A)<0 : root in (p/A, -lam*b)
//  - p<=0 (=> b<0)  : root in (0, -lam*b)
// 12 bisections + 5 safeguarded Newton = fully converged in fp32.
__device__ __forceinline__ float2 heavy_solve(float ux, float uy,
                                              float ax, float ay, float b) {
    float A = fmaf(ax, ax, ay * ay);
    float p = fmaf(ax, ux, ay * uy);
    float N = fmaf(ux, ux, uy * uy);
    float t3;
    if (phi_pos(0.0f, A, p, N, b)) {
        float lo, hi;
        if (p > 0.0f) {
            float tA = p * frcp(fmaxf(A, 1e-30f));
            if (fmaf(tA, INV_LAM, b) >= 0.0f) { lo = 0.0f; hi = tA; }
            else                              { lo = tA;  hi = -LAMC * b; }
        } else {
            lo = 0.0f; hi = -LAMC * b;
        }
        #pragma unroll 1
        for (int k = 0; k < 12; ++k) {
            float mid = 0.5f * (lo + hi);
            bool pos = phi_pos(mid, A, p, N, b);
            lo = pos ? mid : lo;
            hi = pos ? hi : mid;
        }
        t3 = 0.5f * (lo + hi);
        #pragma unroll
        for (int k = 0; k < 5; ++k) {          // safeguarded Newton
            float q   = fmaxf(fmaf(t3, fmaf(t3, A, -2.0f * p), N), EPSC);
            float nrm = fsqrt_(q);
            float R   = fmaf(t3, INV_LAM, b);
            float f   = fmaf(-t3, A, p) - R * nrm;
            float df  = -A - nrm * INV_LAM - R * fmaf(t3, A, -p) * frcp(nrm);
            df = (fabsf(df) > 1e-8f) ? df : -1e-8f;
            bool fp = f > 0.0f;
            lo = fp ? t3 : lo;
            hi = fp ? hi : t3;
            t3 = fminf(fmaxf(t3 - f * frcp(df), lo), hi);
        }
    } else {
        // reference: bisection collapses to 0, then 3 unclamped Newton steps
        t3 = 0.0f;
        #pragma unroll
        for (int k = 0; k < 3; ++k) {
            float q   = fmaxf(fmaf(t3, fmaf(t3, A, -2.0f * p), N), EPSC);
            float nrm = fsqrt_(q);
            float R   = fmaf(t3, INV_LAM, b);
            float f   = fmaf(-t3, A, p) - R * nrm;
            float df  = -A - nrm * INV_LAM - R * fmaf(t3, A, -p) * frcp(nrm);
            df = (fabsf(df) > 1e-8f) ? df : -1e-8f;
            t3 = t3 - f * frcp(df);
        }
    }
    float q3  = fmaxf(fmaf(t3, fmaf(t3, A, -2.0f * p), N), EPSC);
    float k3  = fmaxf(fsqrt_(q3), 1.0f);
    float inv = frcp(k3);
    return make_float2(fmaf(-t3, ax, ux) * inv, fmaf(-t3, ay, uy) * inv);
}

// easy paths; returns true if row is heavy (branch 3). ox/oy always set.
__device__ __forceinline__ bool easy_row(float ux, float uy,
                                         float px, float py, float vx, float vy,
                                         float& ox, float& oy) {
    float ax = -2.0f * px, ay = -2.0f * py;
    float h  = fmaf(px, px, py * py) - 1.0f;
    float b  = fmaf(2.0f, h, -2.0f * fmaf(px, vx, py * vy));
    float A  = fmaf(ax, ax, ay * ay);
    float p  = fmaf(ax, ux, ay * uy);
    float N  = fmaf(ux, ux, uy * uy);
    float s1 = fminf(1.0f, frsq(fmaxf(N, EPSC)));   // min(1, 1/|u|)
    float u1x = ux * s1, u1y = uy * s1;
    ox = u1x; oy = u1y;
    if (fmaf(ax, u1x, ay * u1y) <= b + TOLC) return false;
    float t2  = LAMC * (p - b) * frcp(fmaf(LAMC, A, 1.0f));
    float u2x = fmaf(-t2, ax, ux), u2y = fmaf(-t2, ay, uy);
    if (t2 >= -TOLC && fmaf(u2x, u2x, u2y * u2y) <= 1.0f + TOLC) {
        ox = u2x; oy = u2y; return false;
    }
    return true;
}

// 2 pairs (4 rows) per thread: doubles per-lane ILP (independent easy-path
// chains) and doubles the wave's heavy-compaction pool (256 rows -> ~2x
// lane density in the single heavy pass). Numerics identical to round 6.
__global__ __launch_bounds__(BLK) void cbf_kernel(const float4* __restrict__ u4,
                                                  const float4* __restrict__ obs4,
                                                  const float2* __restrict__ u2v,
                                                  const float*  __restrict__ obs,
                                                  float4* __restrict__ out4,
                                                  int npair) {
    __shared__ short  sid[WPB][RPW];    // wave-local heavy worklist (local row ids)
    __shared__ float2 sres[WPB][RPW];   // wave-local heavy results by local row

    int tid  = threadIdx.x;
    int wave = tid >> 6;
    int lane = tid & 63;
    unsigned long long ltmask = (1ull << lane) - 1ull;

    int base = blockIdx.x * (2 * BLK);      // first pair of this block
    int pA   = base + 128 * wave + lane;    // pair 0 (coalesced)
    int pB   = pA + 64;                     // pair 1 (coalesced)
    bool vA = pA < npair, vB = pB < npair;

    float4 z = make_float4(0.f, 0.f, 0.f, 0.f);
    float4 uA = z, a0 = z, a1 = z, a2 = z;
    float4 uB = z, b0 = z, b1 = z, b2 = z;
    if (vA) { uA = u4[pA]; a0 = obs4[3 * pA]; a1 = obs4[3 * pA + 1]; a2 = obs4[3 * pA + 2]; }
    if (vB) { uB = u4[pB]; b0 = obs4[3 * pB]; b1 = obs4[3 * pB + 1]; b2 = obs4[3 * pB + 2]; }

    // pair layout: rows 2p:   p=(o0.z,o0.w) v=(o1.x,o1.y)
    //              rows 2p+1: p=(o2.x,o2.y) v=(o2.z,o2.w)
    float4 rA = z, rB = z;
    bool h0 = false, h1 = false, h2 = false, h3 = false;
    if (vA) {
        h0 = easy_row(uA.x, uA.y, a0.z, a0.w, a1.x, a1.y, rA.x, rA.y);
        h1 = easy_row(uA.z, uA.w, a2.x, a2.y, a2.z, a2.w, rA.z, rA.w);
    }
    if (vB) {
        h2 = easy_row(uB.x, uB.y, b0.z, b0.w, b1.x, b1.y, rB.x, rB.y);
        h3 = easy_row(uB.z, uB.w, b2.x, b2.y, b2.z, b2.w, rB.z, rB.w);
    }

    // wave-local ballot compaction — no atomics, no block barriers
    unsigned long long m0 = __ballot(h0), m1 = __ballot(h1);
    unsigned long long m2 = __ballot(h2), m3 = __ballot(h3);
    int c0 = __popcll(m0), c1 = __popcll(m1), c2 = __popcll(m2);
    int tot = c0 + c1 + c2 + __popcll(m3);
    // local row ids: pairA -> 2*lane, 2*lane+1 ; pairB -> 128+2*lane, 129+2*lane
    if (h0) sid[wave][__popcll(m0 & ltmask)]                = (short)(2 * lane);
    if (h1) sid[wave][c0 + __popcll(m1 & ltmask)]           = (short)(2 * lane + 1);
    if (h2) sid[wave][c0 + c1 + __popcll(m2 & ltmask)]      = (short)(128 + 2 * lane);
    if (h3) sid[wave][c0 + c1 + c2 + __popcll(m3 & ltmask)] = (short)(129 + 2 * lane);
    __threadfence_block();   // wave lockstep + lgkmcnt drain orders LDS w->r

    int rowbase = 2 * base + wave * RPW;    // global row of local row 0
    #pragma unroll 1
    for (int j = lane; j < tot; j += 64) {
        int lr = sid[wave][j];
        int gr = rowbase + lr;
        float2 uu = u2v[gr];                               // L1/L2-hot
        float2 pr = *(const float2*)(obs + 6 * gr + 2);
        float2 vv = *(const float2*)(obs + 6 * gr + 4);
        float ax = -2.0f * pr.x, ay = -2.0f * pr.y;
        float h  = fmaf(pr.x, pr.x, pr.y * pr.y) - 1.0f;
        float b  = fmaf(2.0f, h, -2.0f * fmaf(pr.x, vv.x, pr.y * vv.y));
        sres[wave][lr] = heavy_solve(uu.x, uu.y, ax, ay, b);
    }
    __threadfence_block();

    if (h0) { float2 s = sres[wave][2 * lane];       rA.x = s.x; rA.y = s.y; }
    if (h1) { float2 s = sres[wave][2 * lane + 1];   rA.z = s.x; rA.w = s.y; }
    if (h2) { float2 s = sres[wave][128 + 2 * lane]; rB.x = s.x; rB.y = s.y; }
    if (h3) { float2 s = sres[wave][129 + 2 * lane]; rB.z = s.x; rB.w = s.y; }
    if (vA) out4[pA] = rA;
    if (vB) out4[pB] = rB;
}

extern "C" void kernel_launch(void* const* d_in, const int* in_sizes, int n_in,
                              void* d_out, int out_size, void* d_ws, size_t ws_size,
                              hipStream_t stream) {
    const float* u_nom = (const float*)d_in[0];
    const float* obs   = (const float*)d_in[1];
    float* out = (float*)d_out;
    int rows   = in_sizes[0] / 2;       // B
    int npair  = rows / 2;              // total pairs
    int blocks = (npair + 2 * BLK - 1) / (2 * BLK);   // 2 pairs per thread
    cbf_kernel<<<blocks, BLK, 0, stream>>>((const float4*)u_nom,
                                           (const float4*)obs,
                                           (const float2*)u_nom, obs,
                                           (float4*)out, npair);
}